// Round 12
// baseline (4508.400 us; speedup 1.0000x reference)
//
#include <hip/hip_runtime.h>
#include <math.h>

#define BATCH 64
#define NREF  256
#define NPTS  2048
#define DIM   128
#define ITERS 100
#define INV_EPS 1000.0f
#define RCH    4                 // rows per register tile in uv
#define NSUB   4                 // sequential sub-chunks per uv block
#define NCHUNK 16                // output chunks (16 rows each): NREF/(RCH*NSUB)

// Scaled (logit) domain throughout: u' = u/eps, v' = v/eps, C' = C/eps.
//
// __launch_bounds__ (measured r5/r7/r8): 2nd arg = min BLOCKS per CU (CUDA
// semantics). (512,4)->64-VGPR cap; (512,3)->85; (512,2)->128. Spill shows as
// GBs of phantom FETCH/WRITE (r7: 4.8GB WRITE on a 67MB-logical kernel).
//
// r11 lesson: occupancy alone (16->24->32 waves) leaves the C stream at
// ~4.8 TB/s. Cause: __syncthreads makes hipcc emit s_waitcnt vmcnt(0) before
// s_barrier -> every global load drains at the row-reduce barriers -> bursty
// issue. Fix (r12): counted-barrier idiom -- ds_write; s_waitcnt lgkmcnt(0);
// raw s_barrier; sched_barrier(0) -- global loads stay in flight; plus a
// depth-1 register double-buffer prefetching the next sub-chunk's C rows.

// ---------- C' via GEMM tiling + inline row norms ----------
__global__ __launch_bounds__(256) void cgemm_kernel(const float* __restrict__ X,
                                                    const float* __restrict__ ref,
                                                    float* __restrict__ C) {
    __shared__ float rs[8 * 128];
    __shared__ float xs[8 * 128];
    __shared__ float r2s[128];
    __shared__ float x2s[128];
    int b  = blockIdx.x >> 5;
    int it = (blockIdx.x >> 4) & 1;
    int jt = blockIdx.x & 15;
    int i0 = it * 128, j0 = jt * 128;
    int t  = threadIdx.x;
    int ti = t >> 4, tj = t & 15;

    int sr = t >> 1;                     // staging row 0..127
    int sh = (t & 1) * 4;                // k-offset 0 or 4
    const float* refp = ref + (size_t)(i0 + sr) * DIM + sh;
    const float* xp   = X + ((size_t)b * NPTS + j0 + sr) * DIM + sh;

    float4 acc[2][2][4];
#pragma unroll
    for (int p = 0; p < 2; ++p)
#pragma unroll
        for (int q = 0; q < 2; ++q)
#pragma unroll
            for (int ii = 0; ii < 4; ++ii)
                acc[p][q][ii] = make_float4(0.f, 0.f, 0.f, 0.f);
    float rsq = 0.f, xsq = 0.f;

    for (int k0 = 0; k0 < DIM; k0 += 8) {
        float4 rv = *(const float4*)(refp + k0);
        float4 xv = *(const float4*)(xp + k0);
        rsq += rv.x * rv.x + rv.y * rv.y + rv.z * rv.z + rv.w * rv.w;
        xsq += xv.x * xv.x + xv.y * xv.y + xv.z * xv.z + xv.w * xv.w;
        __syncthreads();                 // previous compute done before overwrite
        rs[(sh + 0) * 128 + sr] = rv.x; rs[(sh + 1) * 128 + sr] = rv.y;
        rs[(sh + 2) * 128 + sr] = rv.z; rs[(sh + 3) * 128 + sr] = rv.w;
        xs[(sh + 0) * 128 + sr] = xv.x; xs[(sh + 1) * 128 + sr] = xv.y;
        xs[(sh + 2) * 128 + sr] = xv.z; xs[(sh + 3) * 128 + sr] = xv.w;
        __syncthreads();

        const float4* rs4 = (const float4*)rs;
        const float4* xs4 = (const float4*)xs;
#pragma unroll
        for (int k = 0; k < 8; ++k) {
            float4 a0 = rs4[k * 32 + ti];
            float4 a1 = rs4[k * 32 + 16 + ti];
            float4 b0 = xs4[k * 32 + tj];
            float4 b1 = xs4[k * 32 + 16 + tj];
#define FMA4(ACC, S, BV)                                                     \
            ACC.x = fmaf(S, BV.x, ACC.x); ACC.y = fmaf(S, BV.y, ACC.y);      \
            ACC.z = fmaf(S, BV.z, ACC.z); ACC.w = fmaf(S, BV.w, ACC.w);
#define ROW(P, S, II)                                                        \
            FMA4(acc[P][0][II], S, b0) FMA4(acc[P][1][II], S, b1)
            ROW(0, a0.x, 0) ROW(0, a0.y, 1) ROW(0, a0.z, 2) ROW(0, a0.w, 3)
            ROW(1, a1.x, 0) ROW(1, a1.y, 1) ROW(1, a1.z, 2) ROW(1, a1.w, 3)
#undef ROW
#undef FMA4
        }
    }

    rsq += __shfl_xor(rsq, 1);           // combine the two k-halves of row sr
    xsq += __shfl_xor(xsq, 1);
    if ((t & 1) == 0) { r2s[sr] = rsq; x2s[sr] = xsq; }
    __syncthreads();

    float x2v[2][4];
#pragma unroll
    for (int q = 0; q < 2; ++q)
#pragma unroll
        for (int e = 0; e < 4; ++e)
            x2v[q][e] = x2s[q * 64 + tj * 4 + e];

#pragma unroll
    for (int p = 0; p < 2; ++p)
#pragma unroll
        for (int ii = 0; ii < 4; ++ii) {
            int il = p * 64 + ti * 4 + ii;
            float rr = r2s[il];
            float* crow = C + ((size_t)b * NREF + i0 + il) * NPTS + j0;
#pragma unroll
            for (int q = 0; q < 2; ++q) {
                float4 av = acc[p][q][ii];
                float4 o;
                o.x = sqrtf(fmaxf(rr + x2v[q][0] - 2.f * av.x, 0.f)) * INV_EPS;
                o.y = sqrtf(fmaxf(rr + x2v[q][1] - 2.f * av.y, 0.f)) * INV_EPS;
                o.z = sqrtf(fmaxf(rr + x2v[q][2] - 2.f * av.z, 0.f)) * INV_EPS;
                o.w = sqrtf(fmaxf(rr + x2v[q][3] - 2.f * av.w, 0.f)) * INV_EPS;
                *(float4*)(crow + q * 64 + tj * 4) = o;
            }
        }
}

// Counted barrier: drain LDS only (lgkmcnt), NOT global loads (vmcnt).
// sched_barrier(0) pins post-barrier ds_reads from being hoisted above
// the raw s_barrier (llvm.amdgcn.s.barrier is not a memory fence).
#define LDS_BARRIER()                                                        \
    do {                                                                     \
        asm volatile("s_waitcnt lgkmcnt(0)" ::: "memory");                   \
        __builtin_amdgcn_s_barrier();                                        \
        __builtin_amdgcn_sched_barrier(0);                                   \
    } while (0)

// ---------- fused u+column-partial: 512 threads, thread owns ONE float4 col slot ----------
// Block = (b, 16-row output chunk) as 4 sequential 4-row sub-chunks with a
// depth-1 register double-buffer: sub-chunk cc+1's 4 C-row loads are issued at
// the top of iteration cc and stay in flight across BOTH LDS barriers
// (counted-barrier idiom -- no vmcnt drain). Arithmetic order identical to
// r11 -> u/Pl/v bitwise unchanged. ~70 VGPR -> (512,3) 85-cap, 24 waves/CU.
__global__ __launch_bounds__(512, 3) void uv_kernel(const float* __restrict__ C,
                                                    const float* __restrict__ v,
                                                    float* __restrict__ u,
                                                    float* __restrict__ Pl,
                                                    float log_wx) {
    __shared__ float smx[RCH][8];
    __shared__ float sms[RCH][8];
    int b    = blockIdx.x >> 4;
    int co   = blockIdx.x & 15;          // 16-row output chunk
    int t    = threadIdx.x;
    int lane = t & 63;
    int w    = t >> 6;

    const float* Cbase = C + (size_t)(b * NREF + co * (RCH * NSUB)) * NPTS + 4 * t;

    float4 vj = *(const float4*)(v + (size_t)b * NPTS + 4 * t);
    float4 pm = make_float4(-INFINITY, -INFINITY, -INFINITY, -INFINITY);
    float4 ps = make_float4(0.f, 0.f, 0.f, 0.f);

    float4 abuf[2][RCH];                 // compile-time indexed (full unroll)
#pragma unroll
    for (int i = 0; i < RCH; ++i)
        abuf[0][i] = *(const float4*)(Cbase + (size_t)i * NPTS);

#pragma unroll
    for (int cc = 0; cc < NSUB; ++cc) {
        const int cur = cc & 1;
        // prefetch next sub-chunk; these loads remain in flight across the
        // two LDS barriers below (no vmcnt(0) drain with raw s_barrier)
        if (cc + 1 < NSUB) {
#pragma unroll
            for (int i = 0; i < RCH; ++i)
                abuf[cur ^ 1][i] =
                    *(const float4*)(Cbase + (size_t)((cc + 1) * RCH + i) * NPTS);
        }

        float m[RCH], su[RCH];
#pragma unroll
        for (int i = 0; i < RCH; ++i) {
            abuf[cur][i].x = vj.x - abuf[cur][i].x;
            abuf[cur][i].y = vj.y - abuf[cur][i].y;
            abuf[cur][i].z = vj.z - abuf[cur][i].z;
            abuf[cur][i].w = vj.w - abuf[cur][i].w;
            m[i] = fmaxf(fmaxf(abuf[cur][i].x, abuf[cur][i].y),
                         fmaxf(abuf[cur][i].z, abuf[cur][i].w));
        }
#pragma unroll
        for (int i = 0; i < RCH; ++i)
#pragma unroll
            for (int off = 1; off < 64; off <<= 1)
                m[i] = fmaxf(m[i], __shfl_xor(m[i], off));
        if (lane == 0) {
#pragma unroll
            for (int i = 0; i < RCH; ++i) smx[i][w] = m[i];
        }
        LDS_BARRIER();
#pragma unroll
        for (int i = 0; i < RCH; ++i) {
            float mm = smx[i][0];
#pragma unroll
            for (int q = 1; q < 8; ++q) mm = fmaxf(mm, smx[i][q]);
            m[i] = mm;
        }
#pragma unroll
        for (int i = 0; i < RCH; ++i)
            su[i] = __expf(abuf[cur][i].x - m[i]) + __expf(abuf[cur][i].y - m[i])
                  + __expf(abuf[cur][i].z - m[i]) + __expf(abuf[cur][i].w - m[i]);
#pragma unroll
        for (int i = 0; i < RCH; ++i)
#pragma unroll
            for (int off = 1; off < 64; off <<= 1)
                su[i] += __shfl_xor(su[i], off);
        if (lane == 0) {
#pragma unroll
            for (int i = 0; i < RCH; ++i) sms[i][w] = su[i];
        }
        LDS_BARRIER();
#pragma unroll
        for (int i = 0; i < RCH; ++i) {
            float s = ((sms[i][0] + sms[i][1]) + (sms[i][2] + sms[i][3]))
                    + ((sms[i][4] + sms[i][5]) + (sms[i][6] + sms[i][7]));
            su[i] = log_wx - (m[i] + __logf(s));    // su := u_new for row
        }
        int r0 = co * (RCH * NSUB) + cc * RCH;
#pragma unroll
        for (int i = 0; i < RCH; ++i)
            if (t == i) u[b * NREF + r0 + i] = su[i];

        // online column-LSE merge over this sub-chunk; arg = u - C = a + su - v_j
        // (per-column max is essential: row-level shifts underflow entire
        //  columns -- C' spread ~1e4 logit units >> fp32 exp range)
#define CMERGE(Q)                                                            \
        {                                                                    \
            float mq = abuf[cur][0].Q + su[0];                               \
            _Pragma("unroll")                                                \
            for (int i_ = 1; i_ < RCH; ++i_)                                 \
                mq = fmaxf(mq, abuf[cur][i_].Q + su[i_]);                    \
            float nm = fmaxf(pm.Q, mq);                                      \
            float sq_ = ps.Q * __expf(pm.Q - nm);                            \
            _Pragma("unroll")                                                \
            for (int i_ = 0; i_ < RCH; ++i_)                                 \
                sq_ += __expf(abuf[cur][i_].Q + su[i_] - nm);                 \
            pm.Q = nm; ps.Q = sq_;                                           \
        }
        CMERGE(x) CMERGE(y) CMERGE(z) CMERGE(w)
#undef CMERGE
    }

    float4 pl;
    pl.x = (pm.x - vj.x) + __logf(ps.x);
    pl.y = (pm.y - vj.y) + __logf(ps.y);
    pl.z = (pm.z - vj.z) + __logf(ps.z);
    pl.w = (pm.w - vj.w) + __logf(ps.w);
    *(float4*)(Pl + (size_t)(b * NCHUNK + co) * NPTS + 4 * t) = pl;
}

// ---------- merge 16 chunk logits per column -> v ----------
__global__ __launch_bounds__(256) void vmerge_kernel(const float* __restrict__ Pl,
                                                     float* __restrict__ v,
                                                     float log_wy) {
    int b = blockIdx.x >> 3;
    int j = ((blockIdx.x & 7) << 8) + threadIdx.x;
    const float* p = Pl + (size_t)b * NCHUNK * NPTS + j;
    float l[NCHUNK];
#pragma unroll
    for (int c = 0; c < NCHUNK; ++c) l[c] = p[(size_t)c * NPTS];
    float m = l[0];
#pragma unroll
    for (int c = 1; c < NCHUNK; ++c) m = fmaxf(m, l[c]);
    float s = 0.f;
#pragma unroll
    for (int c = 0; c < NCHUNK; ++c) s += __expf(l[c] - m);
    v[(size_t)b * NPTS + j] = log_wy - (m + __logf(s));
}

// ---------- epilogue Path A phase 1: j-split 8, 16-col inner tile ----------
// JT=16: 88 VGPR measured (r9), no spill (WRITE=66MB logical). Swizzle: 4
// quads/row, store q^((r>>3)&3), read q^(g&3).
__global__ __launch_bounds__(512, 2) void out_partialA(const float* __restrict__ C,
                                                       const float* __restrict__ X,
                                                       const float* __restrict__ u,
                                                       const float* __restrict__ v,
                                                       float* __restrict__ Np,
                                                       float* __restrict__ denp) {
    __shared__ float wts[NREF * 16];    // [r][4 float4, swizzled]  16 KB
    __shared__ float xt[16 * DIM];      // [jj][d]                   8 KB
    int b  = blockIdx.x >> 3;
    int jc = blockIdx.x & 7;
    int j0 = jc * 256;
    int t  = threadIdx.x;
    int s  = t & 15;                    // d-slot
    int g  = t >> 4;                    // row group: rows g*8 .. g*8+7

    const float* Cb = C + (size_t)b * NREF * NPTS + j0;
    const float* ub = u + b * NREF;
    const float* vb = v + (size_t)b * NPTS + j0;

    float4 a0[8], a1[8];
    float ws[8];
#pragma unroll
    for (int r = 0; r < 8; ++r) {
        a0[r] = make_float4(0.f, 0.f, 0.f, 0.f);
        a1[r] = make_float4(0.f, 0.f, 0.f, 0.f);
        ws[r] = 0.f;
    }

    for (int jt = 0; jt < 256; jt += 16) {
        // stage wt: 256 rows x 16 cols = 1024 float4, 2 per thread
#pragma unroll
        for (int k = 0; k < 2; ++k) {
            int fidx = t + 512 * k;
            int r = fidx >> 2, q = fidx & 3;
            float4 cv = *(const float4*)(Cb + (size_t)r * NPTS + jt + 4 * q);
            float4 vv = *(const float4*)(vb + jt + 4 * q);
            float uu = ub[r];
            float4 wv;
            wv.x = __expf(uu + vv.x - cv.x);
            wv.y = __expf(uu + vv.y - cv.y);
            wv.z = __expf(uu + vv.z - cv.z);
            wv.w = __expf(uu + vv.w - cv.w);
            int sw = q ^ ((r >> 3) & 3);
            *(float4*)&wts[r * 16 + sw * 4] = wv;
        }
        // stage X-tile: 16 rows x 128 d = 512 float4, 1 per thread (contiguous 8KB)
        const float4* Xb4 = (const float4*)(X + ((size_t)b * NPTS + j0 + jt) * DIM);
        ((float4*)xt)[t] = Xb4[t];
        __syncthreads();

        const float4* xt4 = (const float4*)xt;
#pragma unroll 2
        for (int jp = 0; jp < 8; ++jp) {        // jj = 2*jp, 2*jp+1
            int j1 = 2 * jp;
            float4 xa0 = xt4[j1 * 32 + s];
            float4 xa1 = xt4[j1 * 32 + 16 + s];
            float4 xb0 = xt4[(j1 + 1) * 32 + s];
            float4 xb1 = xt4[(j1 + 1) * 32 + 16 + s];
            int q   = jp >> 1;
            int h   = jp & 1;
            int swb = (q ^ (g & 3)) * 4 + 2 * h;   // float offset within row's 16
#pragma unroll
            for (int rr = 0; rr < 8; ++rr) {
                int r = g * 8 + rr;
                float2 w2 = *(const float2*)&wts[r * 16 + swb];
                a0[rr].x = fmaf(w2.x, xa0.x, a0[rr].x);
                a0[rr].y = fmaf(w2.x, xa0.y, a0[rr].y);
                a0[rr].z = fmaf(w2.x, xa0.z, a0[rr].z);
                a0[rr].w = fmaf(w2.x, xa0.w, a0[rr].w);
                a1[rr].x = fmaf(w2.x, xa1.x, a1[rr].x);
                a1[rr].y = fmaf(w2.x, xa1.y, a1[rr].y);
                a1[rr].z = fmaf(w2.x, xa1.z, a1[rr].z);
                a1[rr].w = fmaf(w2.x, xa1.w, a1[rr].w);
                a0[rr].x = fmaf(w2.y, xb0.x, a0[rr].x);
                a0[rr].y = fmaf(w2.y, xb0.y, a0[rr].y);
                a0[rr].z = fmaf(w2.y, xb0.z, a0[rr].z);
                a0[rr].w = fmaf(w2.y, xb0.w, a0[rr].w);
                a1[rr].x = fmaf(w2.y, xb1.x, a1[rr].x);
                a1[rr].y = fmaf(w2.y, xb1.y, a1[rr].y);
                a1[rr].z = fmaf(w2.y, xb1.z, a1[rr].z);
                a1[rr].w = fmaf(w2.y, xb1.w, a1[rr].w);
                ws[rr] += w2.x + w2.y;
            }
        }
        __syncthreads();
    }

    // plain coalesced stores of this block's partials (disjoint (b,jc) planes)
    float* npb = Np + ((size_t)jc * BATCH * NREF + (size_t)b * NREF) * DIM;
#pragma unroll
    for (int rr = 0; rr < 8; ++rr) {
        int r = g * 8 + rr;
        float4* nrow = (float4*)(npb + (size_t)r * DIM);
        nrow[s]      = a0[rr];
        nrow[16 + s] = a1[rr];
        if (s == 0) denp[(size_t)jc * BATCH * NREF + b * NREF + r] = ws[rr];
    }
}

// ---------- epilogue Path A phase 2: deterministic 8-way combine ----------
__global__ __launch_bounds__(256) void out_finishA(const float* __restrict__ Np,
                                                   const float* __restrict__ denp,
                                                   const float* __restrict__ ref,
                                                   float* __restrict__ out) {
    const int NPL  = BATCH * NREF * DIM / 4;        // float4 per plane
    const int DENP = BATCH * NREF;
    int fidx = blockIdx.x * 256 + threadIdx.x;      // float4 index, 524288 total
    int bi   = fidx >> 5;                           // b*256 + i
    float4 n4 = make_float4(0.f, 0.f, 0.f, 0.f);
    float dn = 0.f;
    const float4* np4 = (const float4*)Np;
#pragma unroll
    for (int jc = 0; jc < 8; ++jc) {                // fixed ascending order
        float4 p = np4[(size_t)jc * NPL + fidx];
        n4.x += p.x; n4.y += p.y; n4.z += p.z; n4.w += p.w;
        dn += denp[(size_t)jc * DENP + bi];
    }
    float inv = 1.0f / (dn + 1e-8f);
    int i = bi & 255;                               // row within batch
    int q = fidx & 31;                              // d-quad
    float4 rf = ((const float4*)ref)[i * 32 + q];
    float4 o;
    o.x = n4.x * inv - rf.x;
    o.y = n4.y * inv - rf.y;
    o.z = n4.z * inv - rf.z;
    o.w = n4.w * inv - rf.w;
    ((float4*)out)[fidx] = o;
}

// ---------- epilogue Path B (fallback, proven round-3): i-split 32-row blocks ----------
__global__ __launch_bounds__(256) void out_kernelB(const float* __restrict__ C,
                                                   const float* __restrict__ X,
                                                   const float* __restrict__ ref,
                                                   const float* __restrict__ u,
                                                   const float* __restrict__ v,
                                                   float* __restrict__ out) {
    __shared__ float wt[32 * 32];       // [row_local][jj]  4 KB
    __shared__ float xt[32 * DIM];      // [jj][d]         16 KB
    int b  = blockIdx.x >> 3;
    int it = blockIdx.x & 7;
    int i0 = it * 32;
    int t  = threadIdx.x;
    int s  = t & 31;                    // d-slot (float4 at d = 4s)
    int g  = t >> 5;                    // rows i0 + g*4 .. +3

    const float* Cb = C + ((size_t)b * NREF + i0) * NPTS;
    const float* vb = v + (size_t)b * NPTS;
    const float* ub = u + (size_t)b * NREF + i0;

    float4 acc[4];
    float wsum[4];
#pragma unroll
    for (int r = 0; r < 4; ++r) { acc[r] = make_float4(0.f, 0.f, 0.f, 0.f); wsum[r] = 0.f; }

    for (int j0 = 0; j0 < NPTS; j0 += 32) {
#pragma unroll
        for (int k = 0; k < 4; ++k) {
            int widx = t + 256 * k;
            int r    = widx >> 5;
            int jj   = widx & 31;
            wt[widx] = __expf(ub[r] + vb[j0 + jj] - Cb[(size_t)r * NPTS + j0 + jj]);
        }
        const float4* Xb4 = (const float4*)(X + ((size_t)b * NPTS + j0) * DIM);
#pragma unroll
        for (int k = 0; k < 4; ++k) {
            int idx = t + 256 * k;
            ((float4*)xt)[idx] = Xb4[idx];
        }
        __syncthreads();

        const float4* xt4 = (const float4*)xt;
#pragma unroll 2
        for (int jj = 0; jj < 32; jj += 4) {
            float4 xv0 = xt4[(jj + 0) * 32 + s];
            float4 xv1 = xt4[(jj + 1) * 32 + s];
            float4 xv2 = xt4[(jj + 2) * 32 + s];
            float4 xv3 = xt4[(jj + 3) * 32 + s];
#pragma unroll
            for (int r = 0; r < 4; ++r) {
                float4 w4 = *(const float4*)&wt[(g * 4 + r) * 32 + jj];
                acc[r].x = fmaf(w4.x, xv0.x, acc[r].x); acc[r].y = fmaf(w4.x, xv0.y, acc[r].y);
                acc[r].z = fmaf(w4.x, xv0.z, acc[r].z); acc[r].w = fmaf(w4.x, xv0.w, acc[r].w);
                acc[r].x = fmaf(w4.y, xv1.x, acc[r].x); acc[r].y = fmaf(w4.y, xv1.y, acc[r].y);
                acc[r].z = fmaf(w4.y, xv1.z, acc[r].z); acc[r].w = fmaf(w4.y, xv1.w, acc[r].w);
                acc[r].x = fmaf(w4.z, xv2.x, acc[r].x); acc[r].y = fmaf(w4.z, xv2.y, acc[r].y);
                acc[r].z = fmaf(w4.z, xv2.z, acc[r].z); acc[r].w = fmaf(w4.z, xv2.w, acc[r].w);
                acc[r].x = fmaf(w4.w, xv3.x, acc[r].x); acc[r].y = fmaf(w4.w, xv3.y, acc[r].y);
                acc[r].z = fmaf(w4.w, xv3.z, acc[r].z); acc[r].w = fmaf(w4.w, xv3.w, acc[r].w);
                wsum[r] += (w4.x + w4.y) + (w4.z + w4.w);
            }
        }
        __syncthreads();
    }

#pragma unroll
    for (int r = 0; r < 4; ++r) {
        int i = i0 + g * 4 + r;
        float dn = wsum[r] + 1e-8f;
        float inv = 1.0f / dn;
        float4 rf = ((const float4*)(ref + (size_t)i * DIM))[s];
        float4 o;
        o.x = acc[r].x * inv - rf.x;
        o.y = acc[r].y * inv - rf.y;
        o.z = acc[r].z * inv - rf.z;
        o.w = acc[r].w * inv - rf.w;
        ((float4*)(out + ((size_t)b * NREF + i) * DIM))[s] = o;
    }
}

extern "C" void kernel_launch(void* const* d_in, const int* in_sizes, int n_in,
                              void* d_out, int out_size, void* d_ws, size_t ws_size,
                              hipStream_t stream) {
    const float* X   = (const float*)d_in[0];
    const float* ref = (const float*)d_in[1];
    float* out = (float*)d_out;

    char* ws = (char*)d_ws;
    size_t o = 0;
    float* C = (float*)(ws + o); o += (size_t)BATCH * NREF * NPTS * sizeof(float);
    float* u = (float*)(ws + o); o += (size_t)BATCH * NREF * sizeof(float);
    float* v = (float*)(ws + o); o += (size_t)BATCH * NPTS * sizeof(float);
    // Pl (loop partials, 8.4 MB) is dead after the loop; Np (67.1 MB) aliases it.
    float* Pl = (float*)(ws + o);
    float* Np = (float*)(ws + o);
    size_t oA = o + (size_t)8 * BATCH * NREF * DIM * sizeof(float);
    float* denp = (float*)(ws + oA);
    oA += (size_t)8 * BATCH * NREF * sizeof(float);
    bool bigws = (ws_size >= oA);       // Path A needs ~202.4 MB total

    const float log_wx = (float)log(1.0 / (double)NREF + 1e-8);
    const float log_wy = (float)log(1.0 / (double)NPTS + 1e-8);

    hipMemsetAsync(v, 0, (size_t)BATCH * NPTS * sizeof(float), stream);

    cgemm_kernel<<<BATCH * 32, 256, 0, stream>>>(X, ref, C);

    for (int t = 0; t < ITERS; ++t) {
        uv_kernel<<<BATCH * NCHUNK, 512, 0, stream>>>(C, v, u, Pl, log_wx);
        vmerge_kernel<<<BATCH * NPTS / 256, 256, 0, stream>>>(Pl, v, log_wy);
    }

    if (bigws) {
        out_partialA<<<BATCH * 8, 512, 0, stream>>>(C, X, u, v, Np, denp);
        out_finishA<<<BATCH * NREF * DIM / 1024, 256, 0, stream>>>(Np, denp, ref, out);
    } else {
        out_kernelB<<<BATCH * 8, 256, 0, stream>>>(C, X, ref, u, v, out);
    }
}

// Round 13
// 3639.781 us; speedup vs baseline: 1.2386x; 1.2386x over previous
//
#include <hip/hip_runtime.h>
#include <math.h>

#define BATCH 64
#define NREF  256
#define NPTS  2048
#define DIM   128
#define ITERS 100
// Base-2 logit domain: C2 = (C/eps)*log2e; u2,v2 likewise scaled. All exp/log
// are raw v_exp_f32/v_log_f32 (2^x / log2 x) -- saves the ln2-scale mul on
// every transcendental (~268M muls/iter, ~3.4us/iter of VALU).
#define C2SCALE 1442.6950408889634f   // INV_EPS * log2(e)
#define RCH    4                 // rows per register tile in uv
#define NSUB   4                 // sequential sub-chunks per uv block
#define NCHUNK 16                // output chunks (16 rows each): NREF/(RCH*NSUB)

#if __has_builtin(__builtin_amdgcn_exp2f)
__device__ __forceinline__ float fexp2(float x) { return __builtin_amdgcn_exp2f(x); }
#else
__device__ __forceinline__ float fexp2(float x) { return exp2f(x); }
#endif
#if __has_builtin(__builtin_amdgcn_logf)
__device__ __forceinline__ float flog2(float x) { return __builtin_amdgcn_logf(x); }
#else
__device__ __forceinline__ float flog2(float x) { return log2f(x); }
#endif

// __launch_bounds__ (measured r5/r7/r8): 2nd arg = min BLOCKS per CU (CUDA
// semantics). (512,4)->64-VGPR cap; (512,3)->85; (512,2)->128. Spill shows as
// GBs of phantom FETCH/WRITE (r7: 4.8GB WRITE on a 67MB-logical kernel).
//
// r10-r12 lesson: the uv loop is VALU-bound (~19 FMA-equiv/element incl. two
// quarter-rate exps), NOT memory-bound -- occupancy (16/24/32 waves) and
// load-pipelining (counted barriers, r12: REGRESSED +5.6us/iter) are flat.
// r13 attacks the VALU op count itself (base-2 domain).

// ---------- C2 via GEMM tiling + inline row norms ----------
__global__ __launch_bounds__(256) void cgemm_kernel(const float* __restrict__ X,
                                                    const float* __restrict__ ref,
                                                    float* __restrict__ C) {
    __shared__ float rs[8 * 128];
    __shared__ float xs[8 * 128];
    __shared__ float r2s[128];
    __shared__ float x2s[128];
    int b  = blockIdx.x >> 5;
    int it = (blockIdx.x >> 4) & 1;
    int jt = blockIdx.x & 15;
    int i0 = it * 128, j0 = jt * 128;
    int t  = threadIdx.x;
    int ti = t >> 4, tj = t & 15;

    int sr = t >> 1;                     // staging row 0..127
    int sh = (t & 1) * 4;                // k-offset 0 or 4
    const float* refp = ref + (size_t)(i0 + sr) * DIM + sh;
    const float* xp   = X + ((size_t)b * NPTS + j0 + sr) * DIM + sh;

    float4 acc[2][2][4];
#pragma unroll
    for (int p = 0; p < 2; ++p)
#pragma unroll
        for (int q = 0; q < 2; ++q)
#pragma unroll
            for (int ii = 0; ii < 4; ++ii)
                acc[p][q][ii] = make_float4(0.f, 0.f, 0.f, 0.f);
    float rsq = 0.f, xsq = 0.f;

    for (int k0 = 0; k0 < DIM; k0 += 8) {
        float4 rv = *(const float4*)(refp + k0);
        float4 xv = *(const float4*)(xp + k0);
        rsq += rv.x * rv.x + rv.y * rv.y + rv.z * rv.z + rv.w * rv.w;
        xsq += xv.x * xv.x + xv.y * xv.y + xv.z * xv.z + xv.w * xv.w;
        __syncthreads();                 // previous compute done before overwrite
        rs[(sh + 0) * 128 + sr] = rv.x; rs[(sh + 1) * 128 + sr] = rv.y;
        rs[(sh + 2) * 128 + sr] = rv.z; rs[(sh + 3) * 128 + sr] = rv.w;
        xs[(sh + 0) * 128 + sr] = xv.x; xs[(sh + 1) * 128 + sr] = xv.y;
        xs[(sh + 2) * 128 + sr] = xv.z; xs[(sh + 3) * 128 + sr] = xv.w;
        __syncthreads();

        const float4* rs4 = (const float4*)rs;
        const float4* xs4 = (const float4*)xs;
#pragma unroll
        for (int k = 0; k < 8; ++k) {
            float4 a0 = rs4[k * 32 + ti];
            float4 a1 = rs4[k * 32 + 16 + ti];
            float4 b0 = xs4[k * 32 + tj];
            float4 b1 = xs4[k * 32 + 16 + tj];
#define FMA4(ACC, S, BV)                                                     \
            ACC.x = fmaf(S, BV.x, ACC.x); ACC.y = fmaf(S, BV.y, ACC.y);      \
            ACC.z = fmaf(S, BV.z, ACC.z); ACC.w = fmaf(S, BV.w, ACC.w);
#define ROW(P, S, II)                                                        \
            FMA4(acc[P][0][II], S, b0) FMA4(acc[P][1][II], S, b1)
            ROW(0, a0.x, 0) ROW(0, a0.y, 1) ROW(0, a0.z, 2) ROW(0, a0.w, 3)
            ROW(1, a1.x, 0) ROW(1, a1.y, 1) ROW(1, a1.z, 2) ROW(1, a1.w, 3)
#undef ROW
#undef FMA4
        }
    }

    rsq += __shfl_xor(rsq, 1);           // combine the two k-halves of row sr
    xsq += __shfl_xor(xsq, 1);
    if ((t & 1) == 0) { r2s[sr] = rsq; x2s[sr] = xsq; }
    __syncthreads();

    float x2v[2][4];
#pragma unroll
    for (int q = 0; q < 2; ++q)
#pragma unroll
        for (int e = 0; e < 4; ++e)
            x2v[q][e] = x2s[q * 64 + tj * 4 + e];

#pragma unroll
    for (int p = 0; p < 2; ++p)
#pragma unroll
        for (int ii = 0; ii < 4; ++ii) {
            int il = p * 64 + ti * 4 + ii;
            float rr = r2s[il];
            float* crow = C + ((size_t)b * NREF + i0 + il) * NPTS + j0;
#pragma unroll
            for (int q = 0; q < 2; ++q) {
                float4 av = acc[p][q][ii];
                float4 o;
                o.x = sqrtf(fmaxf(rr + x2v[q][0] - 2.f * av.x, 0.f)) * C2SCALE;
                o.y = sqrtf(fmaxf(rr + x2v[q][1] - 2.f * av.y, 0.f)) * C2SCALE;
                o.z = sqrtf(fmaxf(rr + x2v[q][2] - 2.f * av.z, 0.f)) * C2SCALE;
                o.w = sqrtf(fmaxf(rr + x2v[q][3] - 2.f * av.w, 0.f)) * C2SCALE;
                *(float4*)(crow + q * 64 + tj * 4) = o;
            }
        }
}

// ---------- fused u+column-partial (r11 structure, base-2 domain) ----------
// Block = (b, 16-row output chunk) processed as 4 sequential 4-row sub-chunks.
// a[4]=16 VGPR tile + online (pm,ps) column merge -> ~58 peak ->
// (512,4) 64-cap, 4 blocks/CU = 32 waves. Grid 1024 = 1 residency round.
__global__ __launch_bounds__(512, 4) void uv_kernel(const float* __restrict__ C,
                                                    const float* __restrict__ v,
                                                    float* __restrict__ u,
                                                    float* __restrict__ Pl,
                                                    float log_wx) {
    __shared__ float smx[RCH][8];
    __shared__ float sms[RCH][8];
    int b    = blockIdx.x >> 4;
    int co   = blockIdx.x & 15;          // 16-row output chunk
    int t    = threadIdx.x;
    int lane = t & 63;
    int w    = t >> 6;

    float4 vj = *(const float4*)(v + (size_t)b * NPTS + 4 * t);
    float4 pm = make_float4(-INFINITY, -INFINITY, -INFINITY, -INFINITY);
    float4 ps = make_float4(0.f, 0.f, 0.f, 0.f);

    for (int cc = 0; cc < NSUB; ++cc) {
        int r0 = co * (RCH * NSUB) + cc * RCH;
        const float* Cb = C + (size_t)(b * NREF + r0) * NPTS;

        float4 a[RCH];
#pragma unroll
        for (int i = 0; i < RCH; ++i)
            a[i] = *(const float4*)(Cb + (size_t)i * NPTS + 4 * t);

        float m[RCH], su[RCH];
#pragma unroll
        for (int i = 0; i < RCH; ++i) {
            a[i].x = vj.x - a[i].x; a[i].y = vj.y - a[i].y;
            a[i].z = vj.z - a[i].z; a[i].w = vj.w - a[i].w;
            m[i] = fmaxf(fmaxf(a[i].x, a[i].y), fmaxf(a[i].z, a[i].w));
        }
#pragma unroll
        for (int i = 0; i < RCH; ++i)
#pragma unroll
            for (int off = 1; off < 64; off <<= 1)
                m[i] = fmaxf(m[i], __shfl_xor(m[i], off));
        if (lane == 0) {
#pragma unroll
            for (int i = 0; i < RCH; ++i) smx[i][w] = m[i];
        }
        __syncthreads();
#pragma unroll
        for (int i = 0; i < RCH; ++i) {
            float mm = smx[i][0];
#pragma unroll
            for (int q = 1; q < 8; ++q) mm = fmaxf(mm, smx[i][q]);
            m[i] = mm;
        }
#pragma unroll
        for (int i = 0; i < RCH; ++i)
            su[i] = fexp2(a[i].x - m[i]) + fexp2(a[i].y - m[i])
                  + fexp2(a[i].z - m[i]) + fexp2(a[i].w - m[i]);
#pragma unroll
        for (int i = 0; i < RCH; ++i)
#pragma unroll
            for (int off = 1; off < 64; off <<= 1)
                su[i] += __shfl_xor(su[i], off);
        if (lane == 0) {
#pragma unroll
            for (int i = 0; i < RCH; ++i) sms[i][w] = su[i];
        }
        __syncthreads();
#pragma unroll
        for (int i = 0; i < RCH; ++i) {
            float s = ((sms[i][0] + sms[i][1]) + (sms[i][2] + sms[i][3]))
                    + ((sms[i][4] + sms[i][5]) + (sms[i][6] + sms[i][7]));
            su[i] = log_wx - (m[i] + flog2(s));     // su := u2_new for row r0+i
        }
#pragma unroll
        for (int i = 0; i < RCH; ++i)
            if (t == i) u[b * NREF + r0 + i] = su[i];

        // fold u into the tile in place: a := (v2 - C2) + u2
#pragma unroll
        for (int i = 0; i < RCH; ++i) {
            a[i].x += su[i]; a[i].y += su[i];
            a[i].z += su[i]; a[i].w += su[i];
        }

        // online column-LSE merge over this sub-chunk (per-column max is
        // essential: row-level shifts underflow entire columns -- C2 spread
        // ~1e4 logit units >> fp32 exp range)
#define CMERGE(Q)                                                            \
        {                                                                    \
            float mq = a[0].Q;                                               \
            _Pragma("unroll")                                                \
            for (int i_ = 1; i_ < RCH; ++i_)                                 \
                mq = fmaxf(mq, a[i_].Q);                                     \
            float nm = fmaxf(pm.Q, mq);                                      \
            float sq_ = ps.Q * fexp2(pm.Q - nm);                             \
            _Pragma("unroll")                                                \
            for (int i_ = 0; i_ < RCH; ++i_)                                 \
                sq_ += fexp2(a[i_].Q - nm);                                  \
            pm.Q = nm; ps.Q = sq_;                                           \
        }
        CMERGE(x) CMERGE(y) CMERGE(z) CMERGE(w)
#undef CMERGE
    }

    float4 pl;
    pl.x = (pm.x - vj.x) + flog2(ps.x);
    pl.y = (pm.y - vj.y) + flog2(ps.y);
    pl.z = (pm.z - vj.z) + flog2(ps.z);
    pl.w = (pm.w - vj.w) + flog2(ps.w);
    *(float4*)(Pl + (size_t)(b * NCHUNK + co) * NPTS + 4 * t) = pl;
}

// ---------- merge 16 chunk logits per column -> v ----------
__global__ __launch_bounds__(256) void vmerge_kernel(const float* __restrict__ Pl,
                                                     float* __restrict__ v,
                                                     float log_wy) {
    int b = blockIdx.x >> 3;
    int j = ((blockIdx.x & 7) << 8) + threadIdx.x;
    const float* p = Pl + (size_t)b * NCHUNK * NPTS + j;
    float l[NCHUNK];
#pragma unroll
    for (int c = 0; c < NCHUNK; ++c) l[c] = p[(size_t)c * NPTS];
    float m = l[0];
#pragma unroll
    for (int c = 1; c < NCHUNK; ++c) m = fmaxf(m, l[c]);
    float s = 0.f;
#pragma unroll
    for (int c = 0; c < NCHUNK; ++c) s += fexp2(l[c] - m);
    v[(size_t)b * NPTS + j] = log_wy - (m + flog2(s));
}

// ---------- epilogue Path A phase 1: j-split 8, 16-col inner tile ----------
// JT=16: 88 VGPR measured (r9), no spill (WRITE=66MB logical). Swizzle: 4
// quads/row, store q^((r>>3)&3), read q^(g&3). w = 2^(u2+v2-C2).
__global__ __launch_bounds__(512, 2) void out_partialA(const float* __restrict__ C,
                                                       const float* __restrict__ X,
                                                       const float* __restrict__ u,
                                                       const float* __restrict__ v,
                                                       float* __restrict__ Np,
                                                       float* __restrict__ denp) {
    __shared__ float wts[NREF * 16];    // [r][4 float4, swizzled]  16 KB
    __shared__ float xt[16 * DIM];      // [jj][d]                   8 KB
    int b  = blockIdx.x >> 3;
    int jc = blockIdx.x & 7;
    int j0 = jc * 256;
    int t  = threadIdx.x;
    int s  = t & 15;                    // d-slot
    int g  = t >> 4;                    // row group: rows g*8 .. g*8+7

    const float* Cb = C + (size_t)b * NREF * NPTS + j0;
    const float* ub = u + b * NREF;
    const float* vb = v + (size_t)b * NPTS + j0;

    float4 a0[8], a1[8];
    float ws[8];
#pragma unroll
    for (int r = 0; r < 8; ++r) {
        a0[r] = make_float4(0.f, 0.f, 0.f, 0.f);
        a1[r] = make_float4(0.f, 0.f, 0.f, 0.f);
        ws[r] = 0.f;
    }

    for (int jt = 0; jt < 256; jt += 16) {
        // stage wt: 256 rows x 16 cols = 1024 float4, 2 per thread
#pragma unroll
        for (int k = 0; k < 2; ++k) {
            int fidx = t + 512 * k;
            int r = fidx >> 2, q = fidx & 3;
            float4 cv = *(const float4*)(Cb + (size_t)r * NPTS + jt + 4 * q);
            float4 vv = *(const float4*)(vb + jt + 4 * q);
            float uu = ub[r];
            float4 wv;
            wv.x = fexp2(uu + vv.x - cv.x);
            wv.y = fexp2(uu + vv.y - cv.y);
            wv.z = fexp2(uu + vv.z - cv.z);
            wv.w = fexp2(uu + vv.w - cv.w);
            int sw = q ^ ((r >> 3) & 3);
            *(float4*)&wts[r * 16 + sw * 4] = wv;
        }
        // stage X-tile: 16 rows x 128 d = 512 float4, 1 per thread (contiguous 8KB)
        const float4* Xb4 = (const float4*)(X + ((size_t)b * NPTS + j0 + jt) * DIM);
        ((float4*)xt)[t] = Xb4[t];
        __syncthreads();

        const float4* xt4 = (const float4*)xt;
#pragma unroll 2
        for (int jp = 0; jp < 8; ++jp) {        // jj = 2*jp, 2*jp+1
            int j1 = 2 * jp;
            float4 xa0 = xt4[j1 * 32 + s];
            float4 xa1 = xt4[j1 * 32 + 16 + s];
            float4 xb0 = xt4[(j1 + 1) * 32 + s];
            float4 xb1 = xt4[(j1 + 1) * 32 + 16 + s];
            int q   = jp >> 1;
            int h   = jp & 1;
            int swb = (q ^ (g & 3)) * 4 + 2 * h;   // float offset within row's 16
#pragma unroll
            for (int rr = 0; rr < 8; ++rr) {
                int r = g * 8 + rr;
                float2 w2 = *(const float2*)&wts[r * 16 + swb];
                a0[rr].x = fmaf(w2.x, xa0.x, a0[rr].x);
                a0[rr].y = fmaf(w2.x, xa0.y, a0[rr].y);
                a0[rr].z = fmaf(w2.x, xa0.z, a0[rr].z);
                a0[rr].w = fmaf(w2.x, xa0.w, a0[rr].w);
                a1[rr].x = fmaf(w2.x, xa1.x, a1[rr].x);
                a1[rr].y = fmaf(w2.x, xa1.y, a1[rr].y);
                a1[rr].z = fmaf(w2.x, xa1.z, a1[rr].z);
                a1[rr].w = fmaf(w2.x, xa1.w, a1[rr].w);
                a0[rr].x = fmaf(w2.y, xb0.x, a0[rr].x);
                a0[rr].y = fmaf(w2.y, xb0.y, a0[rr].y);
                a0[rr].z = fmaf(w2.y, xb0.z, a0[rr].z);
                a0[rr].w = fmaf(w2.y, xb0.w, a0[rr].w);
                a1[rr].x = fmaf(w2.y, xb1.x, a1[rr].x);
                a1[rr].y = fmaf(w2.y, xb1.y, a1[rr].y);
                a1[rr].z = fmaf(w2.y, xb1.z, a1[rr].z);
                a1[rr].w = fmaf(w2.y, xb1.w, a1[rr].w);
                ws[rr] += w2.x + w2.y;
            }
        }
        __syncthreads();
    }

    // plain coalesced stores of this block's partials (disjoint (b,jc) planes)
    float* npb = Np + ((size_t)jc * BATCH * NREF + (size_t)b * NREF) * DIM;
#pragma unroll
    for (int rr = 0; rr < 8; ++rr) {
        int r = g * 8 + rr;
        float4* nrow = (float4*)(npb + (size_t)r * DIM);
        nrow[s]      = a0[rr];
        nrow[16 + s] = a1[rr];
        if (s == 0) denp[(size_t)jc * BATCH * NREF + b * NREF + r] = ws[rr];
    }
}

// ---------- epilogue Path A phase 2: deterministic 8-way combine ----------
__global__ __launch_bounds__(256) void out_finishA(const float* __restrict__ Np,
                                                   const float* __restrict__ denp,
                                                   const float* __restrict__ ref,
                                                   float* __restrict__ out) {
    const int NPL  = BATCH * NREF * DIM / 4;        // float4 per plane
    const int DENP = BATCH * NREF;
    int fidx = blockIdx.x * 256 + threadIdx.x;      // float4 index, 524288 total
    int bi   = fidx >> 5;                           // b*256 + i
    float4 n4 = make_float4(0.f, 0.f, 0.f, 0.f);
    float dn = 0.f;
    const float4* np4 = (const float4*)Np;
#pragma unroll
    for (int jc = 0; jc < 8; ++jc) {                // fixed ascending order
        float4 p = np4[(size_t)jc * NPL + fidx];
        n4.x += p.x; n4.y += p.y; n4.z += p.z; n4.w += p.w;
        dn += denp[(size_t)jc * DENP + bi];
    }
    float inv = 1.0f / (dn + 1e-8f);
    int i = bi & 255;                               // row within batch
    int q = fidx & 31;                              // d-quad
    float4 rf = ((const float4*)ref)[i * 32 + q];
    float4 o;
    o.x = n4.x * inv - rf.x;
    o.y = n4.y * inv - rf.y;
    o.z = n4.z * inv - rf.z;
    o.w = n4.w * inv - rf.w;
    ((float4*)out)[fidx] = o;
}

// ---------- epilogue Path B (fallback, proven round-3): i-split 32-row blocks ----------
__global__ __launch_bounds__(256) void out_kernelB(const float* __restrict__ C,
                                                   const float* __restrict__ X,
                                                   const float* __restrict__ ref,
                                                   const float* __restrict__ u,
                                                   const float* __restrict__ v,
                                                   float* __restrict__ out) {
    __shared__ float wt[32 * 32];       // [row_local][jj]  4 KB
    __shared__ float xt[32 * DIM];      // [jj][d]         16 KB
    int b  = blockIdx.x >> 3;
    int it = blockIdx.x & 7;
    int i0 = it * 32;
    int t  = threadIdx.x;
    int s  = t & 31;                    // d-slot (float4 at d = 4s)
    int g  = t >> 5;                    // rows i0 + g*4 .. +3

    const float* Cb = C + ((size_t)b * NREF + i0) * NPTS;
    const float* vb = v + (size_t)b * NPTS;
    const float* ub = u + (size_t)b * NREF + i0;

    float4 acc[4];
    float wsum[4];
#pragma unroll
    for (int r = 0; r < 4; ++r) { acc[r] = make_float4(0.f, 0.f, 0.f, 0.f); wsum[r] = 0.f; }

    for (int j0 = 0; j0 < NPTS; j0 += 32) {
#pragma unroll
        for (int k = 0; k < 4; ++k) {
            int widx = t + 256 * k;
            int r    = widx >> 5;
            int jj   = widx & 31;
            wt[widx] = fexp2(ub[r] + vb[j0 + jj] - Cb[(size_t)r * NPTS + j0 + jj]);
        }
        const float4* Xb4 = (const float4*)(X + ((size_t)b * NPTS + j0) * DIM);
#pragma unroll
        for (int k = 0; k < 4; ++k) {
            int idx = t + 256 * k;
            ((float4*)xt)[idx] = Xb4[idx];
        }
        __syncthreads();

        const float4* xt4 = (const float4*)xt;
#pragma unroll 2
        for (int jj = 0; jj < 32; jj += 4) {
            float4 xv0 = xt4[(jj + 0) * 32 + s];
            float4 xv1 = xt4[(jj + 1) * 32 + s];
            float4 xv2 = xt4[(jj + 2) * 32 + s];
            float4 xv3 = xt4[(jj + 3) * 32 + s];
#pragma unroll
            for (int r = 0; r < 4; ++r) {
                float4 w4 = *(const float4*)&wt[(g * 4 + r) * 32 + jj];
                acc[r].x = fmaf(w4.x, xv0.x, acc[r].x); acc[r].y = fmaf(w4.x, xv0.y, acc[r].y);
                acc[r].z = fmaf(w4.x, xv0.z, acc[r].z); acc[r].w = fmaf(w4.x, xv0.w, acc[r].w);
                acc[r].x = fmaf(w4.y, xv1.x, acc[r].x); acc[r].y = fmaf(w4.y, xv1.y, acc[r].y);
                acc[r].z = fmaf(w4.y, xv1.z, acc[r].z); acc[r].w = fmaf(w4.y, xv1.w, acc[r].w);
                acc[r].x = fmaf(w4.z, xv2.x, acc[r].x); acc[r].y = fmaf(w4.z, xv2.y, acc[r].y);
                acc[r].z = fmaf(w4.z, xv2.z, acc[r].z); acc[r].w = fmaf(w4.z, xv2.w, acc[r].w);
                acc[r].x = fmaf(w4.w, xv3.x, acc[r].x); acc[r].y = fmaf(w4.w, xv3.y, acc[r].y);
                acc[r].z = fmaf(w4.w, xv3.z, acc[r].z); acc[r].w = fmaf(w4.w, xv3.w, acc[r].w);
                wsum[r] += (w4.x + w4.y) + (w4.z + w4.w);
            }
        }
        __syncthreads();
    }

#pragma unroll
    for (int r = 0; r < 4; ++r) {
        int i = i0 + g * 4 + r;
        float dn = wsum[r] + 1e-8f;
        float inv = 1.0f / dn;
        float4 rf = ((const float4*)(ref + (size_t)i * DIM))[s];
        float4 o;
        o.x = acc[r].x * inv - rf.x;
        o.y = acc[r].y * inv - rf.y;
        o.z = acc[r].z * inv - rf.z;
        o.w = acc[r].w * inv - rf.w;
        ((float4*)(out + ((size_t)b * NREF + i) * DIM))[s] = o;
    }
}

extern "C" void kernel_launch(void* const* d_in, const int* in_sizes, int n_in,
                              void* d_out, int out_size, void* d_ws, size_t ws_size,
                              hipStream_t stream) {
    const float* X   = (const float*)d_in[0];
    const float* ref = (const float*)d_in[1];
    float* out = (float*)d_out;

    char* ws = (char*)d_ws;
    size_t o = 0;
    float* C = (float*)(ws + o); o += (size_t)BATCH * NREF * NPTS * sizeof(float);
    float* u = (float*)(ws + o); o += (size_t)BATCH * NREF * sizeof(float);
    float* v = (float*)(ws + o); o += (size_t)BATCH * NPTS * sizeof(float);
    // Pl (loop partials, 8.4 MB) is dead after the loop; Np (67.1 MB) aliases it.
    float* Pl = (float*)(ws + o);
    float* Np = (float*)(ws + o);
    size_t oA = o + (size_t)8 * BATCH * NREF * DIM * sizeof(float);
    float* denp = (float*)(ws + oA);
    oA += (size_t)8 * BATCH * NREF * sizeof(float);
    bool bigws = (ws_size >= oA);       // Path A needs ~202.4 MB total

    // base-2 logit constants: lw2 = ln(w + 1e-8) * log2(e)
    const float log_wx = (float)(log(1.0 / (double)NREF + 1e-8) * 1.4426950408889634);
    const float log_wy = (float)(log(1.0 / (double)NPTS + 1e-8) * 1.4426950408889634);

    hipMemsetAsync(v, 0, (size_t)BATCH * NPTS * sizeof(float), stream);

    cgemm_kernel<<<BATCH * 32, 256, 0, stream>>>(X, ref, C);

    for (int t = 0; t < ITERS; ++t) {
        uv_kernel<<<BATCH * NCHUNK, 512, 0, stream>>>(C, v, u, Pl, log_wx);
        vmerge_kernel<<<BATCH * NPTS / 256, 256, 0, stream>>>(Pl, v, log_wy);
    }

    if (bigws) {
        out_partialA<<<BATCH * 8, 512, 0, stream>>>(C, X, u, v, Np, denp);
        out_finishA<<<BATCH * NREF * DIM / 1024, 256, 0, stream>>>(Np, denp, ref, out);
    } else {
        out_kernelB<<<BATCH * 8, 256, 0, stream>>>(C, X, ref, u, v, out);
    }
}